// Round 3
// baseline (1891.866 us; speedup 1.0000x reference)
//
#include <hip/hip_runtime.h>
#include <hip/hip_bf16.h>
#include <cmath>

using bf16 = __hip_bfloat16;

#define HH 128
#define WW 128
#define HWSZ (HH * WW)

// Load element i of an EXTERNAL input whose dtype is decided by flag f:
// f=1 -> fp32, f=0 -> bf16. Element-index based so pointer math is dtype-free.
__device__ __forceinline__ float ldin(const void* p, size_t i, int f) {
    return f ? ((const float*)p)[i] : __bfloat162float(((const bf16*)p)[i]);
}

// ---------------- dtype detector ----------------
// If inputs are fp32 (little-endian), even-index ushorts are low mantissa bits:
// interpreted as bf16 they hit exponent 0x00/0xFF ~1/128 of the time. Genuine
// bf16 normal(0,1) data never does. One block, ~µs.
__global__ void detect_kernel(const unsigned short* __restrict__ u, int* __restrict__ flag) {
    __shared__ int s_bad;
    int tid = threadIdx.x;
    if (tid == 0) s_bad = 0;
    __syncthreads();
    int bad = 0;
    for (int i = tid; i < 65536; i += 256) {
        unsigned short v = u[2 * i];
        int e = (v >> 7) & 0xFF;
        if (e == 0xFF || (e == 0 && (v & 0x7FFF))) bad++;
    }
    atomicAdd(&s_bad, bad);
    __syncthreads();
    if (tid == 0) flag[0] = (s_bad > 32) ? 1 : 0;
}

// ---------------- weight -> fp32 pre-conversion ----------------
__global__ void wconv_kernel(const void* __restrict__ nw, const void* __restrict__ fw,
                             const int* __restrict__ flag, float* __restrict__ out) {
    int f = *flag;
    int i = blockIdx.x * 256 + threadIdx.x;
    if (i < 73728)      out[i] = ldin(nw, i, f);
    else if (i < 76032) out[i] = ldin(fw, i - 73728, f);
}

// ---------------- node conv: concat(xprev, skip) -> conv3x3 -> BN -> ReLU ----
// wf: [oc=32][ic=64][9] fp32. xprev: external input (dtype per flag) if
// xprev_ext, else bf16 scratch. skip: layers base + slice (external).
__global__ __launch_bounds__(256) void node_conv(
    const void* __restrict__ xprev, int xprev_ext,
    const void* __restrict__ layers, int skip_slice,
    const float* __restrict__ wf,
    const void* __restrict__ g, const void* __restrict__ be,
    const void* __restrict__ mu, const void* __restrict__ va, int prm,
    const int* __restrict__ flag, bf16* __restrict__ out) {
    __shared__ float tile[8 * 18 * 24];  // stride 24: max 2-way bank aliasing (free)
    const int f  = *flag;
    const int xf = xprev_ext ? f : 0;
    const size_t skip_off = (size_t)skip_slice * 16 * 32 * HWSZ;
    const int tid = threadIdx.x;
    const int x0 = blockIdx.x * 16, y0 = blockIdx.y * 16, b = blockIdx.z;
    const int ty = tid >> 4, tx = tid & 15;

    float acc[32];
#pragma unroll
    for (int i = 0; i < 32; i++) acc[i] = 0.f;

    for (int chunk = 0; chunk < 8; chunk++) {
        __syncthreads();
        const int c0 = chunk * 8;
        for (int idx = tid; idx < 8 * 18 * 18; idx += 256) {
            int c  = idx / 324, rem = idx - c * 324;
            int yy = rem / 18,  xx  = rem - yy * 18;
            int gy = y0 + yy - 1, gx = x0 + xx - 1;
            float v = 0.f;
            if (gy >= 0 && gy < HH && gx >= 0 && gx < WW) {
                int cg = c0 + c;
                size_t off = (size_t)(b * 32 + (cg & 31)) * HWSZ + gy * WW + gx;
                v = (cg < 32) ? ldin(xprev, off, xf) : ldin(layers, skip_off + off, f);
            }
            tile[(c * 18 + yy) * 24 + xx] = v;
        }
        __syncthreads();

        for (int c = 0; c < 8; c++) {
            float p[3][3];
#pragma unroll
            for (int ky = 0; ky < 3; ky++)
#pragma unroll
                for (int kx = 0; kx < 3; kx++)
                    p[ky][kx] = tile[(c * 18 + ty + ky) * 24 + tx + kx];
            const float* wp = wf + (size_t)(c0 + c) * 9;
#pragma unroll
            for (int oc = 0; oc < 32; oc++) {
                const float* wo = wp + oc * 576;  // block-uniform -> scalar loads
#pragma unroll
                for (int ky = 0; ky < 3; ky++)
#pragma unroll
                    for (int kx = 0; kx < 3; kx++)
                        acc[oc] = fmaf(p[ky][kx], wo[ky * 3 + kx], acc[oc]);
            }
        }
    }

    const int y = y0 + ty, x = x0 + tx;
#pragma unroll
    for (int oc = 0; oc < 32; oc++) {
        float s  = ldin(g, prm + oc, f) * rsqrtf(ldin(va, prm + oc, f) + 1e-5f);
        float bb = ldin(be, prm + oc, f) - ldin(mu, prm + oc, f) * s;
        float v  = fmaxf(fmaf(acc[oc], s, bb), 0.f);
        out[(size_t)(b * 32 + oc) * HWSZ + y * WW + x] = __float2bfloat16(v);
    }
}

// ---------------- final conv: 32 -> 8 channels, BN -> tanh ----------------
__global__ __launch_bounds__(256) void final_conv(
    const bf16* __restrict__ xin,
    const float* __restrict__ wf,
    const void* __restrict__ g, const void* __restrict__ be,
    const void* __restrict__ mu, const void* __restrict__ va,
    const int* __restrict__ flag, bf16* __restrict__ out) {
    __shared__ float tile[8 * 18 * 24];
    const int f = *flag;
    const int tid = threadIdx.x;
    const int x0 = blockIdx.x * 16, y0 = blockIdx.y * 16, b = blockIdx.z;
    const int ty = tid >> 4, tx = tid & 15;

    float acc[8];
#pragma unroll
    for (int i = 0; i < 8; i++) acc[i] = 0.f;

    for (int chunk = 0; chunk < 4; chunk++) {
        __syncthreads();
        const int c0 = chunk * 8;
        for (int idx = tid; idx < 8 * 18 * 18; idx += 256) {
            int c  = idx / 324, rem = idx - c * 324;
            int yy = rem / 18,  xx  = rem - yy * 18;
            int gy = y0 + yy - 1, gx = x0 + xx - 1;
            float v = 0.f;
            if (gy >= 0 && gy < HH && gx >= 0 && gx < WW)
                v = __bfloat162float(xin[(size_t)(b * 32 + c0 + c) * HWSZ + gy * WW + gx]);
            tile[(c * 18 + yy) * 24 + xx] = v;
        }
        __syncthreads();

        for (int c = 0; c < 8; c++) {
            float p[3][3];
#pragma unroll
            for (int ky = 0; ky < 3; ky++)
#pragma unroll
                for (int kx = 0; kx < 3; kx++)
                    p[ky][kx] = tile[(c * 18 + ty + ky) * 24 + tx + kx];
#pragma unroll
            for (int oc = 0; oc < 8; oc++) {
                const float* wo = wf + (size_t)(oc * 32 + c0 + c) * 9;
#pragma unroll
                for (int ky = 0; ky < 3; ky++)
#pragma unroll
                    for (int kx = 0; kx < 3; kx++)
                        acc[oc] = fmaf(p[ky][kx], wo[ky * 3 + kx], acc[oc]);
            }
        }
    }

    const int y = y0 + ty, x = x0 + tx;
#pragma unroll
    for (int oc = 0; oc < 8; oc++) {
        float s  = ldin(g, oc, f) * rsqrtf(ldin(va, oc, f) + 1e-5f);
        float bb = ldin(be, oc, f) - ldin(mu, oc, f) * s;
        float v  = tanhf(fmaf(acc[oc], s, bb));
        out[(size_t)(b * 8 + oc) * HWSZ + y * WW + x] = __float2bfloat16(v);
    }
}

// ---------------- depthwise bilinear transpose-conv x2 + ramp adds ----------
// out[oy,ox] = sum_{ky,kx} in[(oy+1-ky)/2,(ox+1-kx)/2]*w[ky,kx] over even/in-range.
__global__ __launch_bounds__(256) void upsample_kernel(
    const bf16* __restrict__ yin,    // [16][8][128][128] bf16 scratch
    const void* __restrict__ upw,    // [8][1][4][4] external
    const int* __restrict__ flag,
    void* __restrict__ out) {        // [16][8][256][256], dtype per flag
    const int f = *flag;
    int i  = blockIdx.x * 256 + threadIdx.x;
    int ox = i & 255;
    int oy = (i >> 8) & 255;
    int c  = (i >> 16) & 7;
    int b  = i >> 19;

    float w[4][4];
#pragma unroll
    for (int ky = 0; ky < 4; ky++)
#pragma unroll
        for (int kx = 0; kx < 4; kx++)
            w[ky][kx] = ldin(upw, c * 16 + ky * 4 + kx, f);

    const bf16* src = yin + (size_t)(b * 8 + c) * HWSZ;
    float acc = 0.f;
#pragma unroll
    for (int ky = 0; ky < 4; ky++) {
        int tyy = oy + 1 - ky;
        if (tyy < 0 || (tyy & 1)) continue;
        int iy = tyy >> 1;
        if (iy >= HH) continue;
#pragma unroll
        for (int kx = 0; kx < 4; kx++) {
            int txx = ox + 1 - kx;
            if (txx < 0 || (txx & 1)) continue;
            int ix = txx >> 1;
            if (ix >= WW) continue;
            acc = fmaf(__bfloat162float(src[iy * WW + ix]), w[ky][kx], acc);
        }
    }
    if (c == 0)      acc += (float)oy * (1.0f / 256.0f);
    else if (c == 1) acc += (float)ox * (1.0f / 256.0f);
    if (f) ((float*)out)[i] = acc;
    else   ((bf16*)out)[i]  = __float2bfloat16(acc);
}

extern "C" void kernel_launch(void* const* d_in, const int* in_sizes, int n_in,
                              void* d_out, int out_size, void* d_ws, size_t ws_size,
                              hipStream_t stream) {
    const void* layers = d_in[0];   // [5][16][32][128][128]
    const void* node_w = d_in[1];   // [4][32][64][3][3]
    const void* ng     = d_in[2];
    const void* nb     = d_in[3];
    const void* nm     = d_in[4];
    const void* nv     = d_in[5];
    const void* fw     = d_in[6];   // [8][32][3][3]
    const void* fg     = d_in[7];
    const void* fb     = d_in[8];
    const void* fm     = d_in[9];
    const void* fv     = d_in[10];
    const void* upw    = d_in[11];  // [8][1][4][4]

    // Workspace: [flag:16B][fp32 weights 76032][S0: bf16 8388608] = 17.08 MB.
    // S1 scratch lives inside d_out (>= 16.78 MB for either out dtype).
    int*   dflag = (int*)d_ws;
    float* wfn   = (float*)((char*)d_ws + 16);
    float* wff   = wfn + 73728;
    bf16*  S0    = (bf16*)(wfn + 76032);
    bf16*  S1    = (bf16*)d_out;

    detect_kernel<<<1, 256, 0, stream>>>((const unsigned short*)layers, dflag);
    wconv_kernel<<<(76032 + 255) / 256, 256, 0, stream>>>(node_w, fw, dflag, wfn);

    dim3 grid(WW / 16, HH / 16, 16), blk(256);

    node_conv<<<grid, blk, 0, stream>>>(layers, 1, layers, 1, wfn,
                                        ng, nb, nm, nv, 0,  dflag, S0);
    node_conv<<<grid, blk, 0, stream>>>(S0, 0, layers, 2, wfn + 18432,
                                        ng, nb, nm, nv, 32, dflag, S1);
    node_conv<<<grid, blk, 0, stream>>>(S1, 0, layers, 3, wfn + 2 * 18432,
                                        ng, nb, nm, nv, 64, dflag, S0);
    node_conv<<<grid, blk, 0, stream>>>(S0, 0, layers, 4, wfn + 3 * 18432,
                                        ng, nb, nm, nv, 96, dflag, S1);
    final_conv<<<grid, blk, 0, stream>>>(S1, wff, fg, fb, fm, fv, dflag, S0);
    upsample_kernel<<<32768, 256, 0, stream>>>(S0, upw, dflag, d_out);
}